// Round 1
// baseline (840.531 us; speedup 1.0000x reference)
//
#include <hip/hip_runtime.h>
#include <stdint.h>

#define N_NODES 20000
#define N_EDGES 320000

typedef __attribute__((ext_vector_type(8)))  __bf16        bf16x8;
typedef __attribute__((ext_vector_type(16))) float         f32x16;
typedef __attribute__((ext_vector_type(4)))  float         f32x4v;
typedef __attribute__((ext_vector_type(2)))  float         f32x2v;
typedef __attribute__((ext_vector_type(8)))  unsigned short us8;
typedef __attribute__((ext_vector_type(4)))  unsigned short us4;
typedef __attribute__((ext_vector_type(2)))  unsigned short us2;

static __device__ __forceinline__ unsigned short cvt_bf16(float f) {
  uint32_t u = __builtin_bit_cast(uint32_t, f);
  u = (u + 0x7fffu + ((u >> 16) & 1u)) >> 16;
  return (unsigned short)u;
}
static __device__ __forceinline__ float cvt_f32(unsigned short h) {
  uint32_t u = ((uint32_t)h) << 16;
  return __builtin_bit_cast(float, u);
}

// ---------------------------------------------------------------------------
// Pack a row-major f32 weight W[K][Ncols] into MFMA fragment order (bf16):
// out[((ks*(Ncols/32) + nt)*64 + lane)*8 + e] = W[ks*16 + (lane>>5)*8 + e][nt*32 + (lane&31)]
// Same formula serves layer-1 A-operand (W1^T role) and layer-2 B-operand.
// ---------------------------------------------------------------------------
__global__ void pack_w(const float* __restrict__ W, unsigned short* __restrict__ out,
                       int K, int Ncols) {
  int idx = blockIdx.x * 256 + threadIdx.x;
  int total = K * Ncols;
  if (idx >= total) return;
  int e    = idx & 7;
  int lane = (idx >> 3) & 63;
  int t    = idx >> 9;
  int ntiles = Ncols >> 5;
  int nt = t % ntiles;
  int ks = t / ntiles;
  int k = ks * 16 + (lane >> 5) * 8 + e;
  int c = nt * 32 + (lane & 31);
  out[idx] = cvt_bf16(W[(size_t)k * Ncols + c]);
}

// ---------------------------------------------------------------------------
// CSR build for segment_sum (receivers are constant across both iterations)
// ---------------------------------------------------------------------------
__global__ void hist_k(const int* __restrict__ recv, int* __restrict__ cnt, int n) {
  int i = blockIdx.x * 256 + threadIdx.x;
  if (i < n) atomicAdd(&cnt[recv[i]], 1);
}

__global__ void scan_k(const int* __restrict__ cnt, int* __restrict__ off,
                       int* __restrict__ cursor, int n) {
  __shared__ int part[1024];
  int t = threadIdx.x;
  int chunk = (n + 1023) / 1024;
  int base = t * chunk;
  int s = 0;
  for (int i = 0; i < chunk; ++i) { int idx = base + i; if (idx < n) s += cnt[idx]; }
  part[t] = s;
  __syncthreads();
  for (int d = 1; d < 1024; d <<= 1) {
    int v = (t >= d) ? part[t - d] : 0;
    __syncthreads();
    part[t] += v;
    __syncthreads();
  }
  int prefix = (t > 0) ? part[t - 1] : 0;
  for (int i = 0; i < chunk; ++i) {
    int idx = base + i;
    if (idx < n) { off[idx] = prefix; cursor[idx] = prefix; prefix += cnt[idx]; }
  }
  if (t == 1023) off[n] = part[1023];
}

__global__ void fill_k(const int* __restrict__ recv, int* __restrict__ cursor,
                       int* __restrict__ eid, int n) {
  int i = blockIdx.x * 256 + threadIdx.x;
  if (i < n) {
    int p = atomicAdd(&cursor[recv[i]], 1);
    eid[p] = i;
  }
}

// agg[n][:] = sum over edges with receiver n of e[edge][:]   (f32 accumulate)
__global__ void agg_k(const unsigned short* __restrict__ eb, const int* __restrict__ off,
                      const int* __restrict__ eid, float* __restrict__ agg, int n) {
  int node = blockIdx.x * 4 + (threadIdx.x >> 6);
  if (node >= n) return;
  int lane = threadIdx.x & 63;
  float a0 = 0.f, a1 = 0.f;
  int s = off[node], t = off[node + 1];
  for (int q = s; q < t; ++q) {
    int ei = eid[q];
    us2 v = *(const us2*)(eb + (size_t)ei * 128 + lane * 2);
    a0 += cvt_f32(v[0]);
    a1 += cvt_f32(v[1]);
  }
  f32x2v r; r[0] = a0; r[1] = a1;
  *(f32x2v*)(agg + (size_t)node * 128 + lane * 2) = r;
}

// pooled[row] = sum_d x[row][d]
__global__ void pool_k(const unsigned short* __restrict__ xb, float* __restrict__ out, int n) {
  int row = blockIdx.x * 4 + (threadIdx.x >> 6);
  if (row >= n) return;
  int lane = threadIdx.x & 63;
  us2 v = *(const us2*)(xb + (size_t)row * 128 + lane * 2);
  float s = cvt_f32(v[0]) + cvt_f32(v[1]);
  #pragma unroll
  for (int d = 32; d > 0; d >>= 1) s += __shfl_xor(s, d, 64);
  if (lane == 0) out[row] = s;
}

// ---------------------------------------------------------------------------
// Fused 2-layer MLP: out = relu(relu(A @ W1 + b1) @ W2 + b2), out dim 128,
// hidden 256, A built per MODE:
//   MODE 0: A[i] = srcf rows (f32, width KIN=128)
//   MODE 1: A[i] = [ x[senders[i]], x[receivers[i]], e[i] ]  (bf16, KIN=384)
//   MODE 2: A[i] = [ x[i] (bf16), agg[i] (f32) ]             (KIN=256)
// Block: 512 threads (8 waves), 256 rows. Layer 1 computed flipped
// (D1^T = W1^T * A^T) so H can be written row-major with b64 stores.
// ---------------------------------------------------------------------------
template <int KIN, int MODE>
__global__ __launch_bounds__(512)
void mlp_kernel(const float* __restrict__ srcf,
                const unsigned short* __restrict__ xb,
                const unsigned short* __restrict__ ebuf,
                const float* __restrict__ aggf,
                const int* __restrict__ senders,
                const int* __restrict__ receivers,
                const unsigned short* __restrict__ P1,
                const float* __restrict__ b1,
                const unsigned short* __restrict__ P2,
                const float* __restrict__ b2,
                unsigned short* __restrict__ dst,
                int nrows) {
  __shared__ __align__(16) unsigned short Hs[256 * 256];  // 128 KB, [row][hidden] swizzled
  __shared__ __align__(16) unsigned short Ws[4096];       // 8 KB weight chunk
  __shared__ __align__(16) unsigned short Rs[4096];       // 8 KB row chunk [256][16]

  const int tid  = threadIdx.x;
  const int lane = tid & 63;
  const int wid  = tid >> 6;        // 0..7
  const int g    = lane >> 5;       // k-group within fragment
  const int l31  = lane & 31;
  const int rowBlock = blockIdx.x << 8;

  // --- stager: each thread owns (row = tid>>1, 16B half = tid&1) ---
  const int srow  = tid >> 1;
  const int shalf = tid & 1;
  int grow = rowBlock + srow;
  if (grow >= nrows) grow = nrows - 1;   // clamp; stores are guarded later
  int sidx = 0, ridx = 0;
  if constexpr (MODE == 1) { sidx = senders[grow]; ridx = receivers[grow]; }

  const int wm = wid >> 2;  // hidden half (0/1)
  const int wn = wid & 3;   // row quarter (64 rows)

  f32x16 acc1[4][2];
#pragma unroll
  for (int a = 0; a < 4; ++a)
#pragma unroll
    for (int b = 0; b < 2; ++b)
#pragma unroll
      for (int q = 0; q < 16; ++q) acc1[a][b][q] = 0.0f;

  constexpr int NK1 = KIN / 16;
#pragma unroll 1
  for (int ks = 0; ks < NK1; ++ks) {
    // stage W1 fragment chunk: 8 KB (8 m-tiles x 1KB)
    *(us8*)(Ws + tid * 8) = *(const us8*)(P1 + (size_t)ks * 4096 + tid * 8);
    // stage row chunk Rs[256][16] bf16
    {
      const int gk = ks * 16 + shalf * 8;
      us8 h;
      if constexpr (MODE == 0) {
        const float* p = srcf + (size_t)grow * KIN + gk;
        f32x4v a = *(const f32x4v*)p;
        f32x4v b4 = *(const f32x4v*)(p + 4);
#pragma unroll
        for (int q = 0; q < 4; ++q) { h[q] = cvt_bf16(a[q]); h[4 + q] = cvt_bf16(b4[q]); }
      } else if constexpr (MODE == 1) {
        const int seg = gk >> 7, ko = gk & 127;
        const unsigned short* p =
            (seg == 0) ? (xb + (size_t)sidx * 128 + ko)
          : (seg == 1) ? (xb + (size_t)ridx * 128 + ko)
                       : (ebuf + (size_t)grow * 128 + ko);
        h = *(const us8*)p;
      } else {
        const int seg = gk >> 7, ko = gk & 127;
        if (seg == 0) {
          h = *(const us8*)(xb + (size_t)grow * 128 + ko);
        } else {
          const float* p = aggf + (size_t)grow * 128 + ko;
          f32x4v a = *(const f32x4v*)p;
          f32x4v b4 = *(const f32x4v*)(p + 4);
#pragma unroll
          for (int q = 0; q < 4; ++q) { h[q] = cvt_bf16(a[q]); h[4 + q] = cvt_bf16(b4[q]); }
        }
      }
      *(us8*)(Rs + srow * 16 + shalf * 8) = h;
    }
    __syncthreads();

    bf16x8 af[4], bfr[2];
#pragma unroll
    for (int mt = 0; mt < 4; ++mt)
      af[mt] = __builtin_bit_cast(bf16x8, *(const us8*)(Ws + (((wm * 4 + mt) << 6) + lane) * 8));
#pragma unroll
    for (int nt = 0; nt < 2; ++nt)
      bfr[nt] = __builtin_bit_cast(bf16x8, *(const us8*)(Rs + (wn * 64 + nt * 32 + l31) * 16 + g * 8));
#pragma unroll
    for (int mt = 0; mt < 4; ++mt)
#pragma unroll
      for (int nt = 0; nt < 2; ++nt)
        acc1[mt][nt] = __builtin_amdgcn_mfma_f32_32x32x16_bf16(af[mt], bfr[nt], acc1[mt][nt], 0, 0, 0);
    __syncthreads();
  }

  // layer-1 epilogue: bias+relu, write H[j][i] bf16, 16B-XOR swizzle per row
#pragma unroll
  for (int mt = 0; mt < 4; ++mt) {
#pragma unroll
    for (int nt = 0; nt < 2; ++nt) {
      const int j = wn * 64 + nt * 32 + l31;
      const unsigned swz = (unsigned)(j & 7) << 4;
#pragma unroll
      for (int rq = 0; rq < 4; ++rq) {
        const int i0 = wm * 128 + mt * 32 + rq * 8 + g * 4;
        const f32x4v bb = *(const f32x4v*)(b1 + i0);
        us4 h;
#pragma unroll
        for (int q = 0; q < 4; ++q) {
          float v = acc1[mt][nt][rq * 4 + q] + bb[q];
          v = fmaxf(v, 0.0f);
          h[q] = cvt_bf16(v);
        }
        *(us4*)((char*)Hs + (size_t)j * 512 + (((unsigned)(i0 * 2)) ^ swz)) = h;
      }
    }
  }
  __syncthreads();

  // layer 2: D2 = H * W2  (M = rows, wave owns rows wid*32..+32, all 128 cols)
  f32x16 acc2[4];
#pragma unroll
  for (int a = 0; a < 4; ++a)
#pragma unroll
    for (int q = 0; q < 16; ++q) acc2[a][q] = 0.0f;

  const int jrow = wid * 32 + l31;
  const unsigned swr = (unsigned)(jrow & 7) << 4;
#pragma unroll 1
  for (int ks = 0; ks < 16; ++ks) {
    if (tid < 256) *(us8*)(Ws + tid * 8) = *(const us8*)(P2 + (size_t)ks * 2048 + tid * 8);
    __syncthreads();
    bf16x8 af = __builtin_bit_cast(bf16x8,
        *(const us8*)((const char*)Hs + (size_t)jrow * 512 + (((unsigned)(ks * 32 + g * 16)) ^ swr)));
#pragma unroll
    for (int nt = 0; nt < 4; ++nt) {
      bf16x8 bf2 = __builtin_bit_cast(bf16x8, *(const us8*)(Ws + ((nt << 6) + lane) * 8));
      acc2[nt] = __builtin_amdgcn_mfma_f32_32x32x16_bf16(af, bf2, acc2[nt], 0, 0, 0);
    }
    __syncthreads();
  }

  // layer-2 epilogue: bias+relu, bf16 store
#pragma unroll
  for (int nt = 0; nt < 4; ++nt) {
    const int c = nt * 32 + l31;
    const float bias = b2[c];
#pragma unroll
    for (int reg = 0; reg < 16; ++reg) {
      const int j = wid * 32 + (reg & 3) + ((reg >> 2) << 3) + g * 4;
      const int row = rowBlock + j;
      if (row < nrows) {
        float v = acc2[nt][reg] + bias;
        v = fmaxf(v, 0.0f);
        dst[(size_t)row * 128 + c] = cvt_bf16(v);
      }
    }
  }
}

// ---------------------------------------------------------------------------
// Workspace layout (bytes)
// ---------------------------------------------------------------------------
static constexpr size_t OFF_X    = 0;                         // N*128*2
static constexpr size_t OFF_E    = 5120000;                   // E*128*2
static constexpr size_t OFF_AGG  = 87040000;                  // N*128*4
static constexpr size_t OFF_PN1  = 97280000;                  // 65536
static constexpr size_t OFF_PN2  = OFF_PN1 + 65536;
static constexpr size_t OFF_PE1  = OFF_PN2 + 65536;
static constexpr size_t OFF_PE2  = OFF_PE1 + 65536;
static constexpr size_t OFF_PD1  = OFF_PE2 + 65536;           // 196608
static constexpr size_t OFF_PD2  = OFF_PD1 + 196608;
static constexpr size_t OFF_PM1  = OFF_PD2 + 65536;           // 131072
static constexpr size_t OFF_PM2  = OFF_PM1 + 131072;
static constexpr size_t OFF_CNT  = OFF_PM2 + 65536;           // N*4
static constexpr size_t OFF_OFFS = OFF_CNT + 80000;           // (N+1)*4
static constexpr size_t OFF_CUR  = OFF_OFFS + 80004;          // N*4
static constexpr size_t OFF_EID  = OFF_CUR + 80000;           // E*4

extern "C" void kernel_launch(void* const* d_in, const int* in_sizes, int n_in,
                              void* d_out, int out_size, void* d_ws, size_t ws_size,
                              hipStream_t stream) {
  const float* nodes = (const float*)d_in[0];
  const float* edges = (const float*)d_in[1];
  const int* senders = (const int*)d_in[2];
  const int* receivers = (const int*)d_in[3];
  const float* Wn1 = (const float*)d_in[4];  const float* bn1 = (const float*)d_in[5];
  const float* Wn2 = (const float*)d_in[6];  const float* bn2 = (const float*)d_in[7];
  const float* We1 = (const float*)d_in[8];  const float* be1 = (const float*)d_in[9];
  const float* We2 = (const float*)d_in[10]; const float* be2 = (const float*)d_in[11];
  const float* Wed1 = (const float*)d_in[12]; const float* bed1 = (const float*)d_in[13];
  const float* Wed2 = (const float*)d_in[14]; const float* bed2 = (const float*)d_in[15];
  const float* Wnd1 = (const float*)d_in[16]; const float* bnd1 = (const float*)d_in[17];
  const float* Wnd2 = (const float*)d_in[18]; const float* bnd2 = (const float*)d_in[19];

  char* ws = (char*)d_ws;
  unsigned short* xb   = (unsigned short*)(ws + OFF_X);
  unsigned short* eb   = (unsigned short*)(ws + OFF_E);
  float*          aggf = (float*)(ws + OFF_AGG);
  unsigned short* Pn1  = (unsigned short*)(ws + OFF_PN1);
  unsigned short* Pn2  = (unsigned short*)(ws + OFF_PN2);
  unsigned short* Pe1  = (unsigned short*)(ws + OFF_PE1);
  unsigned short* Pe2  = (unsigned short*)(ws + OFF_PE2);
  unsigned short* Pd1  = (unsigned short*)(ws + OFF_PD1);
  unsigned short* Pd2  = (unsigned short*)(ws + OFF_PD2);
  unsigned short* Pm1  = (unsigned short*)(ws + OFF_PM1);
  unsigned short* Pm2  = (unsigned short*)(ws + OFF_PM2);
  int* cnt    = (int*)(ws + OFF_CNT);
  int* offs   = (int*)(ws + OFF_OFFS);
  int* cursor = (int*)(ws + OFF_CUR);
  int* eid    = (int*)(ws + OFF_EID);
  float* outp = (float*)d_out;

  // pack all 8 weight matrices into MFMA fragment order (bf16)
  pack_w<<<128, 256, 0, stream>>>(Wn1, Pn1, 128, 256);
  pack_w<<<128, 256, 0, stream>>>(Wn2, Pn2, 256, 128);
  pack_w<<<128, 256, 0, stream>>>(We1, Pe1, 128, 256);
  pack_w<<<128, 256, 0, stream>>>(We2, Pe2, 256, 128);
  pack_w<<<384, 256, 0, stream>>>(Wed1, Pd1, 384, 256);
  pack_w<<<128, 256, 0, stream>>>(Wed2, Pd2, 256, 128);
  pack_w<<<256, 256, 0, stream>>>(Wnd1, Pm1, 256, 256);
  pack_w<<<128, 256, 0, stream>>>(Wnd2, Pm2, 256, 128);

  // CSR for segment_sum over receivers (constant across iterations)
  hipMemsetAsync(cnt, 0, (size_t)N_NODES * 4, stream);
  hist_k<<<1250, 256, 0, stream>>>(receivers, cnt, N_EDGES);
  scan_k<<<1, 1024, 0, stream>>>(cnt, offs, cursor, N_NODES);
  fill_k<<<1250, 256, 0, stream>>>(receivers, cursor, eid, N_EDGES);

  const int nodeBlocks = (N_NODES + 255) / 256;  // 79
  const int edgeBlocks = N_EDGES / 256;          // 1250

  // embed stage
  mlp_kernel<128, 0><<<nodeBlocks, 512, 0, stream>>>(
      nodes, nullptr, nullptr, nullptr, nullptr, nullptr,
      Pn1, bn1, Pn2, bn2, xb, N_NODES);
  mlp_kernel<128, 0><<<edgeBlocks, 512, 0, stream>>>(
      edges, nullptr, nullptr, nullptr, nullptr, nullptr,
      Pe1, be1, Pe2, be2, eb, N_EDGES);

  for (int it = 0; it < 2; ++it) {
    mlp_kernel<384, 1><<<edgeBlocks, 512, 0, stream>>>(
        nullptr, xb, eb, nullptr, senders, receivers,
        Pd1, bed1, Pd2, bed2, eb, N_EDGES);
    agg_k<<<(N_NODES + 3) / 4, 256, 0, stream>>>(eb, offs, eid, aggf, N_NODES);
    mlp_kernel<256, 2><<<nodeBlocks, 512, 0, stream>>>(
        nullptr, xb, nullptr, aggf, nullptr, nullptr,
        Pm1, bnd1, Pm2, bnd2, xb, N_NODES);
    pool_k<<<(N_NODES + 3) / 4, 256, 0, stream>>>(xb, outp + (size_t)it * N_NODES, N_NODES);
  }
}

// Round 2
// 639.680 us; speedup vs baseline: 1.3140x; 1.3140x over previous
//
#include <hip/hip_runtime.h>
#include <stdint.h>

#define N_NODES 20000
#define N_EDGES 320000

typedef __attribute__((ext_vector_type(8)))  __bf16        bf16x8;
typedef __attribute__((ext_vector_type(16))) float         f32x16;
typedef __attribute__((ext_vector_type(4)))  float         f32x4v;
typedef __attribute__((ext_vector_type(8)))  unsigned short us8;
typedef __attribute__((ext_vector_type(4)))  unsigned short us4;
typedef __attribute__((ext_vector_type(2)))  unsigned short us2;

static __device__ __forceinline__ unsigned short cvt_bf16(float f) {
  uint32_t u = __builtin_bit_cast(uint32_t, f);
  u = (u + 0x7fffu + ((u >> 16) & 1u)) >> 16;
  return (unsigned short)u;
}
static __device__ __forceinline__ float cvt_f32(unsigned short h) {
  uint32_t u = ((uint32_t)h) << 16;
  return __builtin_bit_cast(float, u);
}

// async global->LDS, 16B per lane; LDS dest = wave-uniform base + lane*16
static __device__ __forceinline__ void gll16(const void* g, void* l) {
  __builtin_amdgcn_global_load_lds(
      (const __attribute__((address_space(1))) unsigned int*)g,
      (__attribute__((address_space(3))) unsigned int*)l, 16, 0, 0);
}

// ---------------------------------------------------------------------------
// Pack row-major f32 W[K][Ncols] into MFMA A/B fragment order (bf16):
// out[((ks*(Ncols/32)+nt)*64+lane)*8+e] = W[ks*16+(lane>>5)*8+e][nt*32+(lane&31)]
// (verified in R1)
// ---------------------------------------------------------------------------
__global__ void pack_w(const float* __restrict__ W, unsigned short* __restrict__ out,
                       int K, int Ncols) {
  int idx = blockIdx.x * 256 + threadIdx.x;
  int total = K * Ncols;
  if (idx >= total) return;
  int e    = idx & 7;
  int lane = (idx >> 3) & 63;
  int t    = idx >> 9;
  int ntiles = Ncols >> 5;
  int nt = t % ntiles;
  int ks = t / ntiles;
  int k = ks * 16 + (lane >> 5) * 8 + e;
  int c = nt * 32 + (lane & 31);
  out[idx] = cvt_bf16(W[(size_t)k * Ncols + c]);
}

// ---------------------------------------------------------------------------
// CSR build for segment_sum (receivers constant across iterations)
// ---------------------------------------------------------------------------
__global__ void hist_k(const int* __restrict__ recv, int* __restrict__ cnt, int n) {
  int i = blockIdx.x * 256 + threadIdx.x;
  if (i < n) atomicAdd(&cnt[recv[i]], 1);
}

__global__ void scan_k(const int* __restrict__ cnt, int* __restrict__ off,
                       int* __restrict__ cursor, int n) {
  __shared__ int part[1024];
  int t = threadIdx.x;
  int chunk = (n + 1023) / 1024;
  int base = t * chunk;
  int s = 0;
  for (int i = 0; i < chunk; ++i) { int idx = base + i; if (idx < n) s += cnt[idx]; }
  part[t] = s;
  __syncthreads();
  for (int d = 1; d < 1024; d <<= 1) {
    int v = (t >= d) ? part[t - d] : 0;
    __syncthreads();
    part[t] += v;
    __syncthreads();
  }
  int prefix = (t > 0) ? part[t - 1] : 0;
  for (int i = 0; i < chunk; ++i) {
    int idx = base + i;
    if (idx < n) { off[idx] = prefix; cursor[idx] = prefix; prefix += cnt[idx]; }
  }
  if (t == 1023) off[n] = part[1023];
}

__global__ void fill_k(const int* __restrict__ recv, int* __restrict__ cursor,
                       int* __restrict__ eid, int n) {
  int i = blockIdx.x * 256 + threadIdx.x;
  if (i < n) {
    int p = atomicAdd(&cursor[recv[i]], 1);
    eid[p] = i;
  }
}

// agg[n][:] = sum_{edges -> n} e[edge][:], f32 accumulate, bf16 out
__global__ void agg_k(const unsigned short* __restrict__ eb, const int* __restrict__ off,
                      const int* __restrict__ eid, unsigned short* __restrict__ aggb, int n) {
  int node = blockIdx.x * 4 + (threadIdx.x >> 6);
  if (node >= n) return;
  int lane = threadIdx.x & 63;
  float a0 = 0.f, a1 = 0.f;
  int s = off[node], t = off[node + 1];
  for (int q = s; q < t; ++q) {
    int ei = eid[q];
    us2 v = *(const us2*)(eb + (size_t)ei * 128 + lane * 2);
    a0 += cvt_f32(v[0]);
    a1 += cvt_f32(v[1]);
  }
  us2 r; r[0] = cvt_bf16(a0); r[1] = cvt_bf16(a1);
  *(us2*)(aggb + (size_t)node * 128 + lane * 2) = r;
}

// ---------------------------------------------------------------------------
// Fused 2-layer MLP: out = relu(relu(A@W1+b1)@W2+b2), 64 rows/block, 256 thr.
//  MODE 0: A = srcf (f32, KIN=128)        [reg-staged T14 split]
//  MODE 1: A = [x[snd], x[rcv], e]  bf16  [global_load_lds gather]
//  MODE 2: A = [x, agg]             bf16  [global_load_lds]
// Layer 1 flipped (D1^T = W1f * A^T) so H lands row-chunked in registers.
// All LDS tiles slot-major [slot][row][16B] -> conflict-free b128 reads.
// T3 minimum 2-phase: stage(next) at step top, one __syncthreads per step.
// ---------------------------------------------------------------------------
template <int KIN, int MODE, int POOL>
__global__ __launch_bounds__(256, 3)
void mlp_kernel(const float* __restrict__ srcf,
                const unsigned short* __restrict__ xb,
                const unsigned short* __restrict__ ebuf,
                const unsigned short* __restrict__ aggb,
                const int* __restrict__ senders,
                const int* __restrict__ receivers,
                const unsigned short* __restrict__ P1,
                const float* __restrict__ b1,
                const unsigned short* __restrict__ P2,
                const float* __restrict__ b2,
                unsigned short* __restrict__ dst,
                float* __restrict__ pool_out,
                int nrows) {
  // smemA: L1 stage region (Rs dbuf 2x4KB @0, Ws dbuf 2x16KB @8KB) -> 40KB
  //        aliased with Hs [32 slots][64 rows][8 shorts] = 32KB (used after L1)
  __shared__ __align__(16) unsigned short smemA[20480];
  // smemB: L2 W2 dbuf 2x4KB; reused as pool partials after L2
  __shared__ __align__(16) unsigned short smemB[4096];

  unsigned short* RsS = smemA;                 // [2][4][64][8] shorts
  unsigned short* WsS = smemA + 4096;          // [2][8192] shorts
  unsigned short* Hs  = smemA;                 // [32][64][8] shorts (after L1)
  unsigned short* W2S = smemB;                 // [2][2048] shorts

  const int tid  = threadIdx.x;
  const int lane = tid & 63;
  const int wid  = tid >> 6;        // 0..3
  const int g    = lane >> 5;
  const int l31  = lane & 31;
  const int rowBlock = blockIdx.x << 6;   // 64 rows/block

  // stager identity for Rs: slot = wid, row = lane
  int grow0 = rowBlock + lane;
  if (grow0 >= nrows) grow0 = nrows - 1;
  int sidx = 0, ridx = 0;
  if constexpr (MODE == 1) { sidx = senders[grow0]; ridx = receivers[grow0]; }

  const int wm = wid >> 1;  // hidden half (4 mt tiles of 32)
  const int wn = wid & 1;   // row half (32 rows)

  f32x4v pa, pb;  // MODE 0 pending f32 row chunk

  // ---- staging helpers ----
  auto stageRows = [&](int ks, int bsel) {
    if constexpr (MODE == 0) {
      const float* p = srcf + (size_t)grow0 * KIN + ks * 32 + wid * 8;
      pa = *(const f32x4v*)p;
      pb = *(const f32x4v*)(p + 4);
    } else {
      const int gk = ks * 32 + wid * 8;       // wave-uniform
      const int seg = gk >> 7, ko = gk & 127;
      const unsigned short* src;
      if constexpr (MODE == 1) {
        src = (seg == 0) ? xb + (size_t)sidx * 128 + ko
            : (seg == 1) ? xb + (size_t)ridx * 128 + ko
                         : ebuf + (size_t)grow0 * 128 + ko;
      } else {
        src = (seg == 0) ? xb + (size_t)grow0 * 128 + ko
                         : aggb + (size_t)grow0 * 128 + ko;
      }
      gll16(src, RsS + bsel * 2048 + wid * 512);
    }
  };
  auto writeRows0 = [&](int bsel) {   // MODE 0 late ds_write
    us8 h;
#pragma unroll
    for (int q = 0; q < 4; ++q) { h[q] = cvt_bf16(pa[q]); h[4 + q] = cvt_bf16(pb[q]); }
    *(us8*)(RsS + bsel * 2048 + wid * 512 + lane * 8) = h;
  };
  auto stageW1 = [&](int ks, int bsel) {
    const unsigned short* src = P1 + (size_t)ks * 8192;
    unsigned short* wb = WsS + bsel * 8192;
#pragma unroll
    for (int c = 0; c < 4; ++c)
      gll16(src + c * 2048 + tid * 8, wb + c * 2048 + wid * 512);
  };
  auto stageW2 = [&](int s, int bsel) {
    gll16(P2 + (size_t)s * 2048 + tid * 8, W2S + bsel * 2048 + wid * 512);
  };

  // ================= layer 1 =================
  f32x16 acc1[4];
#pragma unroll
  for (int a = 0; a < 4; ++a)
#pragma unroll
    for (int q = 0; q < 16; ++q) acc1[a][q] = 0.0f;

  constexpr int NK1 = KIN / 32;   // 4 / 8 / 12

  stageRows(0, 0);
  stageW1(0, 0);
  if constexpr (MODE == 0) writeRows0(0);
  __syncthreads();

#pragma unroll 1
  for (int ks = 0; ks < NK1; ++ks) {
    const int cur = ks & 1;
    if (ks + 1 < NK1) { stageRows(ks + 1, cur ^ 1); stageW1(ks + 1, cur ^ 1); }

    const unsigned short* wc = WsS + cur * 8192;
    const unsigned short* rc = RsS + cur * 2048;
    bf16x8 af[2][4], br[2];
#pragma unroll
    for (int u = 0; u < 2; ++u) {
      br[u] = __builtin_bit_cast(bf16x8,
              *(const us8*)(rc + (u * 2 + g) * 512 + (wn * 32 + l31) * 8));
#pragma unroll
      for (int mt = 0; mt < 4; ++mt)
        af[u][mt] = __builtin_bit_cast(bf16x8,
              *(const us8*)(wc + u * 4096 + ((wm * 4 + mt) * 64 + lane) * 8));
    }
#pragma unroll
    for (int u = 0; u < 2; ++u)
#pragma unroll
      for (int mt = 0; mt < 4; ++mt)
        acc1[mt] = __builtin_amdgcn_mfma_f32_32x32x16_bf16(af[u][mt], br[u], acc1[mt], 0, 0, 0);

    if constexpr (MODE == 0) { if (ks + 1 < NK1) writeRows0(cur ^ 1); }
    __syncthreads();
  }

  // prefetch first W2 chunk while writing Hs
  stageW2(0, 0);

  // layer-1 epilogue: bias+relu -> Hs slot-major [32][64][8]
#pragma unroll
  for (int mt = 0; mt < 4; ++mt) {
#pragma unroll
    for (int rq = 0; rq < 4; ++rq) {
      const int i0 = wm * 128 + mt * 32 + rq * 8 + g * 4;
      const f32x4v bb = *(const f32x4v*)(b1 + i0);
      us4 h;
#pragma unroll
      for (int q = 0; q < 4; ++q) {
        float v = acc1[mt][rq * 4 + q] + bb[q];
        h[q] = cvt_bf16(fmaxf(v, 0.0f));
      }
      const int j = wn * 32 + l31;
      const int slot = i0 >> 3;
      *(us4*)(Hs + slot * 512 + j * 8 + g * 4) = h;
    }
  }
  __syncthreads();

  // ================= layer 2 =================
  const int jm = wid >> 1, jn = wid & 1;
  f32x16 acc2[2];
#pragma unroll
  for (int a = 0; a < 2; ++a)
#pragma unroll
    for (int q = 0; q < 16; ++q) acc2[a][q] = 0.0f;

#pragma unroll 1
  for (int s = 0; s < 16; ++s) {
    const int cur = s & 1;
    if (s + 1 < 16) stageW2(s + 1, cur ^ 1);
    bf16x8 afr = __builtin_bit_cast(bf16x8,
        *(const us8*)(Hs + (s * 2 + g) * 512 + (jm * 32 + l31) * 8));
#pragma unroll
    for (int nt = 0; nt < 2; ++nt) {
      bf16x8 bf2 = __builtin_bit_cast(bf16x8,
          *(const us8*)(W2S + cur * 2048 + ((jn * 2 + nt) * 64 + lane) * 8));
      acc2[nt] = __builtin_amdgcn_mfma_f32_32x32x16_bf16(afr, bf2, acc2[nt], 0, 0, 0);
    }
    __syncthreads();
  }

  // layer-2 epilogue: bias+relu, bf16 store (+ fused pool row-sums)
  float* Ps = (float*)smemB;   // [2][64] partials; W2S dead after last barrier
#pragma unroll
  for (int reg = 0; reg < 16; ++reg) {
    const int j = jm * 32 + (reg & 3) + ((reg >> 2) << 3) + g * 4;
    const int row = rowBlock + j;
    float vsum = 0.0f;
#pragma unroll
    for (int nt = 0; nt < 2; ++nt) {
      const int c = (jn * 2 + nt) * 32 + l31;
      float v = acc2[nt][reg] + b2[c];
      v = fmaxf(v, 0.0f);
      vsum += v;
      if (row < nrows) dst[(size_t)row * 128 + c] = cvt_bf16(v);
    }
    if constexpr (POOL) {
#pragma unroll
      for (int m = 1; m <= 16; m <<= 1) vsum += __shfl_xor(vsum, m, 64);
      if (l31 == 0) Ps[jn * 64 + j] = vsum;
    }
  }
  if constexpr (POOL) {
    __syncthreads();
    if (tid < 64) {
      const int row = rowBlock + tid;
      if (row < nrows) pool_out[row] = Ps[tid] + Ps[64 + tid];
    }
  }
}

// ---------------------------------------------------------------------------
// Workspace layout (bytes)
// ---------------------------------------------------------------------------
static constexpr size_t OFF_X    = 0;                          // N*128*2
static constexpr size_t OFF_E    = 5120000;                    // E*128*2
static constexpr size_t OFF_AGG  = 87040000;                   // N*128*2 (bf16)
static constexpr size_t OFF_PN1  = 92160000;                   // 65536
static constexpr size_t OFF_PN2  = OFF_PN1 + 65536;
static constexpr size_t OFF_PE1  = OFF_PN2 + 65536;
static constexpr size_t OFF_PE2  = OFF_PE1 + 65536;
static constexpr size_t OFF_PD1  = OFF_PE2 + 65536;            // 196608
static constexpr size_t OFF_PD2  = OFF_PD1 + 196608;
static constexpr size_t OFF_PM1  = OFF_PD2 + 65536;            // 131072
static constexpr size_t OFF_PM2  = OFF_PM1 + 131072;
static constexpr size_t OFF_CNT  = OFF_PM2 + 65536;            // N*4
static constexpr size_t OFF_OFFS = OFF_CNT + 80000;            // (N+1)*4
static constexpr size_t OFF_CUR  = OFF_OFFS + 80004;           // N*4
static constexpr size_t OFF_EID  = OFF_CUR + 80000;            // E*4

extern "C" void kernel_launch(void* const* d_in, const int* in_sizes, int n_in,
                              void* d_out, int out_size, void* d_ws, size_t ws_size,
                              hipStream_t stream) {
  const float* nodes = (const float*)d_in[0];
  const float* edges = (const float*)d_in[1];
  const int* senders = (const int*)d_in[2];
  const int* receivers = (const int*)d_in[3];
  const float* Wn1 = (const float*)d_in[4];  const float* bn1 = (const float*)d_in[5];
  const float* Wn2 = (const float*)d_in[6];  const float* bn2 = (const float*)d_in[7];
  const float* We1 = (const float*)d_in[8];  const float* be1 = (const float*)d_in[9];
  const float* We2 = (const float*)d_in[10]; const float* be2 = (const float*)d_in[11];
  const float* Wed1 = (const float*)d_in[12]; const float* bed1 = (const float*)d_in[13];
  const float* Wed2 = (const float*)d_in[14]; const float* bed2 = (const float*)d_in[15];
  const float* Wnd1 = (const float*)d_in[16]; const float* bnd1 = (const float*)d_in[17];
  const float* Wnd2 = (const float*)d_in[18]; const float* bnd2 = (const float*)d_in[19];

  char* ws = (char*)d_ws;
  unsigned short* xb   = (unsigned short*)(ws + OFF_X);
  unsigned short* eb   = (unsigned short*)(ws + OFF_E);
  unsigned short* aggb = (unsigned short*)(ws + OFF_AGG);
  unsigned short* Pn1  = (unsigned short*)(ws + OFF_PN1);
  unsigned short* Pn2  = (unsigned short*)(ws + OFF_PN2);
  unsigned short* Pe1  = (unsigned short*)(ws + OFF_PE1);
  unsigned short* Pe2  = (unsigned short*)(ws + OFF_PE2);
  unsigned short* Pd1  = (unsigned short*)(ws + OFF_PD1);
  unsigned short* Pd2  = (unsigned short*)(ws + OFF_PD2);
  unsigned short* Pm1  = (unsigned short*)(ws + OFF_PM1);
  unsigned short* Pm2  = (unsigned short*)(ws + OFF_PM2);
  int* cnt    = (int*)(ws + OFF_CNT);
  int* offs   = (int*)(ws + OFF_OFFS);
  int* cursor = (int*)(ws + OFF_CUR);
  int* eid    = (int*)(ws + OFF_EID);
  float* outp = (float*)d_out;

  // pack all 8 weight matrices into MFMA fragment order (bf16)
  pack_w<<<128, 256, 0, stream>>>(Wn1, Pn1, 128, 256);
  pack_w<<<128, 256, 0, stream>>>(Wn2, Pn2, 256, 128);
  pack_w<<<128, 256, 0, stream>>>(We1, Pe1, 128, 256);
  pack_w<<<128, 256, 0, stream>>>(We2, Pe2, 256, 128);
  pack_w<<<384, 256, 0, stream>>>(Wed1, Pd1, 384, 256);
  pack_w<<<128, 256, 0, stream>>>(Wed2, Pd2, 256, 128);
  pack_w<<<256, 256, 0, stream>>>(Wnd1, Pm1, 256, 256);
  pack_w<<<128, 256, 0, stream>>>(Wnd2, Pm2, 256, 128);

  // CSR for segment_sum over receivers
  hipMemsetAsync(cnt, 0, (size_t)N_NODES * 4, stream);
  hist_k<<<1250, 256, 0, stream>>>(receivers, cnt, N_EDGES);
  scan_k<<<1, 1024, 0, stream>>>(cnt, offs, cursor, N_NODES);
  fill_k<<<1250, 256, 0, stream>>>(receivers, cursor, eid, N_EDGES);

  const int nodeBlocks = (N_NODES + 63) / 64;   // 313
  const int edgeBlocks = N_EDGES / 64;          // 5000

  // embed stage
  mlp_kernel<128, 0, 0><<<nodeBlocks, 256, 0, stream>>>(
      nodes, nullptr, nullptr, nullptr, nullptr, nullptr,
      Pn1, bn1, Pn2, bn2, xb, nullptr, N_NODES);
  mlp_kernel<128, 0, 0><<<edgeBlocks, 256, 0, stream>>>(
      edges, nullptr, nullptr, nullptr, nullptr, nullptr,
      Pe1, be1, Pe2, be2, eb, nullptr, N_EDGES);

  for (int it = 0; it < 2; ++it) {
    mlp_kernel<384, 1, 0><<<edgeBlocks, 256, 0, stream>>>(
        nullptr, xb, eb, nullptr, senders, receivers,
        Pd1, bed1, Pd2, bed2, eb, nullptr, N_EDGES);
    agg_k<<<(N_NODES + 3) / 4, 256, 0, stream>>>(eb, offs, eid, aggb, N_NODES);
    mlp_kernel<256, 2, 1><<<nodeBlocks, 256, 0, stream>>>(
        nullptr, xb, nullptr, aggb, nullptr, nullptr,
        Pm1, bnd1, Pm2, bnd2, xb, outp + (size_t)it * N_NODES, N_NODES);
  }
}